// Round 6
// baseline (472.991 us; speedup 1.0000x reference)
//
#include <hip/hip_runtime.h>
#include <hip/hip_bf16.h>
#include <cstddef>

#define NHOP 10
#define NN 200000
#define FF 128
#define HIDD 256
#define CCC 100
#define NEG_SLOPE_C 0.2f

typedef __attribute__((ext_vector_type(8))) short bf16x8;   // 8 bf16 = 4 VGPR
typedef __attribute__((ext_vector_type(4))) short bf16x4;
typedef __attribute__((ext_vector_type(4))) float f32x4;

__device__ __forceinline__ short f2bfs(float x){
  return __builtin_bit_cast(short, __float2bfloat16(x));    // native v_cvt, RNE
}
__device__ __forceinline__ f32x4 mfma16(bf16x8 a, bf16x8 b, f32x4 c){
  return __builtin_amdgcn_mfma_f32_16x16x32_bf16(a, b, c, 0, 0, 0);
}
__device__ __forceinline__ float leakyf(float x){ return x >= 0.f ? x : NEG_SLOPE_C*x; }

// ---------------- Kernel 0: weight prep (bf16 + transpose + pad) ----------------
__global__ __launch_bounds__(256) void prep_weights(
    const float* __restrict__ Wo1, const float* __restrict__ Wl1,
    const float* __restrict__ Wo2, const float* __restrict__ Wl2,
    unsigned short* __restrict__ Wo1T, unsigned short* __restrict__ Wl1T,
    unsigned short* __restrict__ Wo2T, unsigned short* __restrict__ Wl2T)
{
  const int id = blockIdx.x*256 + threadIdx.x;          // 0..32767
  {
    const int c = id >> 7, k = id & 127;                // layout [256][128]
    Wo1T[id] = (unsigned short)f2bfs(Wo1[(size_t)k*HIDD + c]);           // Wo1 [128][256]
    Wl1T[id] = (k < CCC) ? (unsigned short)f2bfs(Wl1[(size_t)k*HIDD + c]) : 0;  // pad k
  }
  if (id < 112*256){
    const int c = id >> 8, k = id & 255;                // layout [112][256]
    Wo2T[id] = (c < CCC) ? (unsigned short)f2bfs(Wo2[(size_t)k*CCC + c]) : 0;   // pad c
    Wl2T[id] = (c < CCC) ? (unsigned short)f2bfs(Wl2[(size_t)k*CCC + c]) : 0;
  }
}

// ---------------- Kernel 1: hop attention -> right (N x F, bf16) ----------------
// R1-proven structure: 1 node/wave, 2 cols/lane, full-wave butterfly, ~85 VGPR,
// high occupancy. Only change vs R1: bf16 output store.
__global__ __launch_bounds__(256) void attn_right_kernel(
    const float* __restrict__ feat,   // H,N,F
    const float* __restrict__ Watt,   // 2F
    const float* __restrict__ batt,   // 1
    unsigned short* __restrict__ rightb)  // N,F bf16
{
  const int lane = threadIdx.x & 63;
  const int n = blockIdx.x * 4 + (threadIdx.x >> 6);

  const float2 w1 = *reinterpret_cast<const float2*>(Watt + 2*lane);
  const float2 w2 = *reinterpret_cast<const float2*>(Watt + FF + 2*lane);
  const float b = batt[0];

  float2 f[NHOP];
  float p1[NHOP], p2[NHOP];
  const float* fp = feat + (size_t)n*FF + 2*lane;
  #pragma unroll
  for (int i=0;i<NHOP;i++){
    f[i] = *reinterpret_cast<const float2*>(fp + (size_t)i*((size_t)NN*FF));
    p1[i] = f[i].x*w1.x + f[i].y*w1.y;
    p2[i] = f[i].x*w2.x + f[i].y*w2.y;
  }
  #pragma unroll
  for (int m=32;m>0;m>>=1){
    #pragma unroll
    for (int i=0;i<NHOP;i++){
      p1[i] += __shfl_xor(p1[i], m, 64);
      p2[i] += __shfl_xor(p2[i], m, 64);
    }
  }
  float sc[NHOP];
  sc[0] = leakyf(p1[0] + p2[0] + b);
  #pragma unroll
  for (int i=1;i<NHOP;i++){
    float mx = sc[0];
    #pragma unroll
    for (int j=1;j<i;j++) mx = fmaxf(mx, sc[j]);
    float Z = 0.f, hs = 0.f;
    #pragma unroll
    for (int j=0;j<i;j++){
      const float e = __expf(sc[j]-mx);
      Z += e;
      hs = fmaf(e, p1[j], hs);
    }
    sc[i] = leakyf(hs/Z + p2[i] + b);
  }
  float mx = sc[0];
  #pragma unroll
  for (int j=1;j<NHOP;j++) mx = fmaxf(mx, sc[j]);
  float Z = 0.f;
  float e[NHOP];
  #pragma unroll
  for (int j=0;j<NHOP;j++){ e[j] = __expf(sc[j]-mx); Z += e[j]; }
  const float inv = 1.f/Z;
  float rx = 0.f, ry = 0.f;
  #pragma unroll
  for (int j=0;j<NHOP;j++){
    const float a = e[j]*inv;
    rx = fmaf(a, f[j].x, rx);
    ry = fmaf(a, f[j].y, ry);
  }
  ushort2 st; st.x = (unsigned short)f2bfs(rx); st.y = (unsigned short)f2bfs(ry);
  *reinterpret_cast<ushort2*>(rightb + (size_t)n*FF + 2*lane) = st;
}

// ---------------- Kernel 2: MFMA MLP ----------------
__device__ __forceinline__ void scatter_h(unsigned short* sH, f32x4 h, float bias,
                                          float alpha, int c, int nt, int lq)
{
  #pragma unroll
  for (int j=0;j<4;++j){
    float v = h[j] + bias;
    v = v >= 0.f ? v : alpha*v;
    const int n = nt*16 + lq*4 + j;
    *reinterpret_cast<unsigned short*>((char*)sH + n*512 + ((2*c) ^ ((n&7)<<4))) =
        (unsigned short)f2bfs(v);
  }
}

__device__ __forceinline__ void gemm2_accum(const unsigned short* sH,
    const unsigned short* __restrict__ W2T, f32x4 (&o)[2][4],
    const int w, const int lr, const int lq)
{
  #pragma unroll
  for (int i2=0; i2<2; ++i2){
    const int ct2 = 2*w + i2;
    if (ct2 < 7){
      bf16x8 b2[8];
      #pragma unroll
      for (int kk=0; kk<8; ++kk)
        b2[kk] = *reinterpret_cast<const bf16x8*>(W2T + (size_t)(ct2*16+lr)*256 + kk*32 + lq*8);
      #pragma unroll
      for (int nt=0; nt<4; ++nt){
        const int row = nt*16 + lr;
        #pragma unroll
        for (int kk=0; kk<8; ++kk){
          const bf16x8 a2 = *reinterpret_cast<const bf16x8*>(
              (const char*)sH + row*512 + ((kk*64 + lq*16) ^ ((row&7)<<4)));
          o[i2][nt] = mfma16(a2, b2[kk], o[i2][nt]);
        }
      }
    }
  }
}

__device__ __forceinline__ bf16x8 label_frag(const float* __restrict__ label,
                                             size_t gnode, int kk, int lq)
{
  bf16x8 r = (bf16x8){0,0,0,0,0,0,0,0};
  const float* base = label + gnode*CCC;
  if (kk < 3){
    const float4 va = *reinterpret_cast<const float4*>(base + kk*32 + lq*8);
    const float4 vb = *reinterpret_cast<const float4*>(base + kk*32 + lq*8 + 4);
    r[0]=f2bfs(va.x); r[1]=f2bfs(va.y); r[2]=f2bfs(va.z); r[3]=f2bfs(va.w);
    r[4]=f2bfs(vb.x); r[5]=f2bfs(vb.y); r[6]=f2bfs(vb.z); r[7]=f2bfs(vb.w);
  } else if (lq == 0){
    const float4 va = *reinterpret_cast<const float4*>(base + 96);   // cols 96..99
    r[0]=f2bfs(va.x); r[1]=f2bfs(va.y); r[2]=f2bfs(va.z); r[3]=f2bfs(va.w);
  }
  return r;
}

__global__ __launch_bounds__(256) void mlp_mfma_kernel(
    const unsigned short* __restrict__ rightb, const float* __restrict__ label,
    const unsigned short* __restrict__ Wo1T, const float* __restrict__ bo1, const float* __restrict__ aop,
    const unsigned short* __restrict__ Wo2T, const float* __restrict__ bo2,
    const unsigned short* __restrict__ Wl1T, const float* __restrict__ bl1, const float* __restrict__ alp,
    const unsigned short* __restrict__ Wl2T, const float* __restrict__ bl2,
    float* __restrict__ out)
{
  __shared__ __align__(16) unsigned short sH[64*256];   // 32 KB h (swizzled) / f32 bounce
  const int t = threadIdx.x;
  const int w = t >> 6, lane = t & 63, lr = lane & 15, lq = lane >> 4;
  const size_t nb = (size_t)blockIdx.x * 64;
  const float ao = aop[0], al = alp[0];

  f32x4 o[2][4];
  #pragma unroll
  for (int i2=0; i2<2; ++i2){
    const int ct2 = 2*w + i2;
    const int c2 = ct2*16 + lr;
    const float init = (ct2 < 7 && c2 < CCC) ? (bo2[c2] + bl2[c2]) : 0.f;
    #pragma unroll
    for (int nt=0; nt<4; ++nt) o[i2][nt] = (f32x4){init, init, init, init};
  }

  // ---- branch 1 GEMM1: all B-frags loaded ONCE, each A-frag loaded ONCE ----
  {
    bf16x8 B1[4][4];
    float b1c[4];
    #pragma unroll
    for (int q=0; q<4; ++q){
      const int c = (w*4 + q)*16 + lr;
      b1c[q] = bo1[c];
      #pragma unroll
      for (int kk=0; kk<4; ++kk)
        B1[q][kk] = *reinterpret_cast<const bf16x8*>(Wo1T + (size_t)c*128 + kk*32 + lq*8);
    }
    #pragma unroll
    for (int nt=0; nt<4; ++nt){
      const int row = nt*16 + lr;
      bf16x8 a[4];
      #pragma unroll
      for (int kk=0; kk<4; ++kk)
        a[kk] = *reinterpret_cast<const bf16x8*>(rightb + (nb + row)*FF + kk*32 + lq*8);
      f32x4 h[4];
      #pragma unroll
      for (int q=0; q<4; ++q) h[q] = (f32x4){0.f,0.f,0.f,0.f};
      #pragma unroll
      for (int kk=0; kk<4; ++kk)
        #pragma unroll
        for (int q=0; q<4; ++q)
          h[q] = mfma16(a[kk], B1[q][kk], h[q]);
      #pragma unroll
      for (int q=0; q<4; ++q)
        scatter_h(sH, h[q], b1c[q], ao, (w*4 + q)*16 + lr, nt, lq);
    }
  }
  __syncthreads();
  gemm2_accum(sH, Wo2T, o, w, lr, lq);
  __syncthreads();

  // ---- branch 2 GEMM1: A = label (fp32 -> bf16 in regs) ----
  {
    bf16x8 B1[4][4];
    float b1c[4];
    #pragma unroll
    for (int q=0; q<4; ++q){
      const int c = (w*4 + q)*16 + lr;
      b1c[q] = bl1[c];
      #pragma unroll
      for (int kk=0; kk<4; ++kk)
        B1[q][kk] = *reinterpret_cast<const bf16x8*>(Wl1T + (size_t)c*128 + kk*32 + lq*8);
    }
    #pragma unroll
    for (int nt=0; nt<4; ++nt){
      const int row = nt*16 + lr;
      bf16x8 a[4];
      #pragma unroll
      for (int kk=0; kk<4; ++kk)
        a[kk] = label_frag(label, nb + row, kk, lq);
      f32x4 h[4];
      #pragma unroll
      for (int q=0; q<4; ++q) h[q] = (f32x4){0.f,0.f,0.f,0.f};
      #pragma unroll
      for (int kk=0; kk<4; ++kk)
        #pragma unroll
        for (int q=0; q<4; ++q)
          h[q] = mfma16(a[kk], B1[q][kk], h[q]);
      #pragma unroll
      for (int q=0; q<4; ++q)
        scatter_h(sH, h[q], b1c[q], al, (w*4 + q)*16 + lr, nt, lq);
    }
  }
  __syncthreads();
  gemm2_accum(sH, Wl2T, o, w, lr, lq);
  __syncthreads();   // sH free for f32 bounce

  // ---- epilogue: bounce through LDS for coalesced stores ----
  float* sF = reinterpret_cast<float*>(sH);
  #pragma unroll
  for (int i2=0; i2<2; ++i2){
    const int ct2 = 2*w + i2;
    const int c2 = ct2*16 + lr;
    if (ct2 < 7 && c2 < CCC){
      #pragma unroll
      for (int nt=0; nt<4; ++nt){
        #pragma unroll
        for (int j=0; j<4; ++j)
          sF[(nt*16 + lq*4 + j)*CCC + c2] = o[i2][nt][j];
      }
    }
  }
  __syncthreads();
  #pragma unroll
  for (int p=0; p<25; ++p){
    const int idx = p*256 + t;
    out[nb*CCC + idx] = sF[idx];
  }
}

extern "C" void kernel_launch(void* const* d_in, const int* in_sizes, int n_in,
                              void* d_out, int out_size, void* d_ws, size_t ws_size,
                              hipStream_t stream) {
  const float* feat  = (const float*)d_in[0];
  const float* label = (const float*)d_in[1];
  const float* Watt  = (const float*)d_in[2];
  const float* batt  = (const float*)d_in[3];
  const float* Wo1   = (const float*)d_in[4];
  const float* bo1   = (const float*)d_in[5];
  const float* aop   = (const float*)d_in[6];
  const float* Wo2   = (const float*)d_in[7];
  const float* bo2   = (const float*)d_in[8];
  const float* Wl1   = (const float*)d_in[9];
  const float* bl1   = (const float*)d_in[10];
  const float* alp   = (const float*)d_in[11];
  const float* Wl2   = (const float*)d_in[12];
  const float* bl2   = (const float*)d_in[13];
  float* out = (float*)d_out;

  unsigned short* rightb = (unsigned short*)d_ws;          // N*F bf16 = 51.2 MB
  unsigned short* Wo1T = rightb + (size_t)NN*FF;           // [256][128]
  unsigned short* Wl1T = Wo1T + 256*128;                   // [256][128]
  unsigned short* Wo2T = Wl1T + 256*128;                   // [112][256]
  unsigned short* Wl2T = Wo2T + 112*256;                   // [112][256]

  prep_weights<<<128, 256, 0, stream>>>(Wo1, Wl1, Wo2, Wl2, Wo1T, Wl1T, Wo2T, Wl2T);
  attn_right_kernel<<<NN/4, 256, 0, stream>>>(feat, Watt, batt, rightb);
  mlp_mfma_kernel<<<NN/64, 256, 0, stream>>>(rightb, label,
                                             Wo1T, bo1, aop, Wo2T, bo2,
                                             Wl1T, bl1, alp, Wl2T, bl2, out);
}

// Round 7
// 462.403 us; speedup vs baseline: 1.0229x; 1.0229x over previous
//
#include <hip/hip_runtime.h>
#include <hip/hip_bf16.h>
#include <cstddef>

#define NHOP 10
#define NN 200000
#define FF 128
#define HIDD 256
#define CCC 100
#define NEG_SLOPE_C 0.2f

typedef __attribute__((ext_vector_type(8))) short bf16x8;   // 8 bf16 = 4 VGPR
typedef __attribute__((ext_vector_type(4))) short bf16x4;
typedef __attribute__((ext_vector_type(4))) float f32x4;

__device__ __forceinline__ short f2bfs(float x){
  return __builtin_bit_cast(short, __float2bfloat16(x));    // native v_cvt, RNE
}
__device__ __forceinline__ f32x4 mfma16(bf16x8 a, bf16x8 b, f32x4 c){
  return __builtin_amdgcn_mfma_f32_16x16x32_bf16(a, b, c, 0, 0, 0);
}
__device__ __forceinline__ float leakyf(float x){ return x >= 0.f ? x : NEG_SLOPE_C*x; }

// ---------------- Kernel 0: weight prep (bf16 + transpose + pad) ----------------
__global__ __launch_bounds__(256) void prep_weights(
    const float* __restrict__ Wo1, const float* __restrict__ Wl1,
    const float* __restrict__ Wo2, const float* __restrict__ Wl2,
    unsigned short* __restrict__ Wo1T, unsigned short* __restrict__ Wl1T,
    unsigned short* __restrict__ Wo2T, unsigned short* __restrict__ Wl2T)
{
  const int id = blockIdx.x*256 + threadIdx.x;          // 0..32767
  {
    const int c = id >> 7, k = id & 127;                // layout [256][128]
    Wo1T[id] = (unsigned short)f2bfs(Wo1[(size_t)k*HIDD + c]);           // Wo1 [128][256]
    Wl1T[id] = (k < CCC) ? (unsigned short)f2bfs(Wl1[(size_t)k*HIDD + c]) : 0;  // pad k
  }
  if (id < 112*256){
    const int c = id >> 8, k = id & 255;                // layout [112][256]
    Wo2T[id] = (c < CCC) ? (unsigned short)f2bfs(Wo2[(size_t)k*CCC + c]) : 0;   // pad c
    Wl2T[id] = (c < CCC) ? (unsigned short)f2bfs(Wl2[(size_t)k*CCC + c]) : 0;
  }
}

// ---------------- Kernel 1: hop attention -> right (N x F, bf16) ----------------
// R1-proven: 1 node/wave, 2 cols/lane, ~60 VGPR -> 8 waves/SIMD. bf16 store.
__global__ __launch_bounds__(256) void attn_right_kernel(
    const float* __restrict__ feat,   // H,N,F
    const float* __restrict__ Watt,   // 2F
    const float* __restrict__ batt,   // 1
    unsigned short* __restrict__ rightb)  // N,F bf16
{
  const int lane = threadIdx.x & 63;
  const int n = blockIdx.x * 4 + (threadIdx.x >> 6);

  const float2 w1 = *reinterpret_cast<const float2*>(Watt + 2*lane);
  const float2 w2 = *reinterpret_cast<const float2*>(Watt + FF + 2*lane);
  const float b = batt[0];

  float2 f[NHOP];
  float p1[NHOP], p2[NHOP];
  const float* fp = feat + (size_t)n*FF + 2*lane;
  #pragma unroll
  for (int i=0;i<NHOP;i++){
    f[i] = *reinterpret_cast<const float2*>(fp + (size_t)i*((size_t)NN*FF));
    p1[i] = f[i].x*w1.x + f[i].y*w1.y;
    p2[i] = f[i].x*w2.x + f[i].y*w2.y;
  }
  #pragma unroll
  for (int m=32;m>0;m>>=1){
    #pragma unroll
    for (int i=0;i<NHOP;i++){
      p1[i] += __shfl_xor(p1[i], m, 64);
      p2[i] += __shfl_xor(p2[i], m, 64);
    }
  }
  float sc[NHOP];
  sc[0] = leakyf(p1[0] + p2[0] + b);
  #pragma unroll
  for (int i=1;i<NHOP;i++){
    float mx = sc[0];
    #pragma unroll
    for (int j=1;j<i;j++) mx = fmaxf(mx, sc[j]);
    float Z = 0.f, hs = 0.f;
    #pragma unroll
    for (int j=0;j<i;j++){
      const float e = __expf(sc[j]-mx);
      Z += e;
      hs = fmaf(e, p1[j], hs);
    }
    sc[i] = leakyf(hs/Z + p2[i] + b);
  }
  float mx = sc[0];
  #pragma unroll
  for (int j=1;j<NHOP;j++) mx = fmaxf(mx, sc[j]);
  float Z = 0.f;
  float e[NHOP];
  #pragma unroll
  for (int j=0;j<NHOP;j++){ e[j] = __expf(sc[j]-mx); Z += e[j]; }
  const float inv = 1.f/Z;
  float rx = 0.f, ry = 0.f;
  #pragma unroll
  for (int j=0;j<NHOP;j++){
    const float a = e[j]*inv;
    rx = fmaf(a, f[j].x, rx);
    ry = fmaf(a, f[j].y, ry);
  }
  ushort2 st; st.x = (unsigned short)f2bfs(rx); st.y = (unsigned short)f2bfs(ry);
  *reinterpret_cast<ushort2*>(rightb + (size_t)n*FF + 2*lane) = st;
}

// ---------------- Kernel 2: MFMA MLP (R4-proven mlpB structure, verbatim) ----------------
__device__ __forceinline__ void scatter_h(unsigned short* sH, f32x4 h, float bias,
                                          float alpha, int c, int nt, int lq)
{
  #pragma unroll
  for (int j=0;j<4;++j){
    float v = h[j] + bias;
    v = v >= 0.f ? v : alpha*v;
    const int n = nt*16 + lq*4 + j;
    *reinterpret_cast<unsigned short*>((char*)sH + n*512 + ((2*c) ^ ((n&7)<<4))) =
        (unsigned short)f2bfs(v);
  }
}

__device__ __forceinline__ void gemm2_accum(const unsigned short* sH,
    const unsigned short* __restrict__ W2T, f32x4 (&o)[2][4],
    const int w, const int lr, const int lq)
{
  #pragma unroll
  for (int i2=0; i2<2; ++i2){
    const int ct2 = 2*w + i2;
    if (ct2 < 7){
      bf16x8 b2[8];
      #pragma unroll
      for (int kk=0; kk<8; ++kk)
        b2[kk] = *reinterpret_cast<const bf16x8*>(W2T + (size_t)(ct2*16+lr)*256 + kk*32 + lq*8);
      #pragma unroll
      for (int nt=0; nt<4; ++nt){
        const int row = nt*16 + lr;
        #pragma unroll
        for (int kk=0; kk<8; ++kk){
          const bf16x8 a2 = *reinterpret_cast<const bf16x8*>(
              (const char*)sH + row*512 + ((kk*64 + lq*16) ^ ((row&7)<<4)));
          o[i2][nt] = mfma16(a2, b2[kk], o[i2][nt]);
        }
      }
    }
  }
}

__device__ __forceinline__ bf16x8 label_frag(const float* __restrict__ label,
                                             size_t gnode, int kk, int lq)
{
  bf16x8 r = (bf16x8){0,0,0,0,0,0,0,0};
  const float* base = label + gnode*CCC;
  if (kk < 3){
    const float4 va = *reinterpret_cast<const float4*>(base + kk*32 + lq*8);
    const float4 vb = *reinterpret_cast<const float4*>(base + kk*32 + lq*8 + 4);
    r[0]=f2bfs(va.x); r[1]=f2bfs(va.y); r[2]=f2bfs(va.z); r[3]=f2bfs(va.w);
    r[4]=f2bfs(vb.x); r[5]=f2bfs(vb.y); r[6]=f2bfs(vb.z); r[7]=f2bfs(vb.w);
  } else if (lq == 0){
    const float4 va = *reinterpret_cast<const float4*>(base + 96);   // cols 96..99
    r[0]=f2bfs(va.x); r[1]=f2bfs(va.y); r[2]=f2bfs(va.z); r[3]=f2bfs(va.w);
  }
  return r;
}

__global__ __launch_bounds__(256) void mlp_mfma_kernel(
    const unsigned short* __restrict__ rightb, const float* __restrict__ label,
    const unsigned short* __restrict__ Wo1T, const float* __restrict__ bo1, const float* __restrict__ aop,
    const unsigned short* __restrict__ Wo2T, const float* __restrict__ bo2,
    const unsigned short* __restrict__ Wl1T, const float* __restrict__ bl1, const float* __restrict__ alp,
    const unsigned short* __restrict__ Wl2T, const float* __restrict__ bl2,
    float* __restrict__ out)
{
  __shared__ __align__(16) unsigned short sH[64*256];   // 32 KB h (swizzled), only LDS
  const int t = threadIdx.x;
  const int w = t >> 6, lane = t & 63, lr = lane & 15, lq = lane >> 4;
  const size_t nb = (size_t)blockIdx.x * 64;
  const float ao = aop[0], al = alp[0];

  // init out accumulators with final biases
  f32x4 o[2][4];
  #pragma unroll
  for (int i2=0; i2<2; ++i2){
    const int ct2 = 2*w + i2;
    const int c2 = ct2*16 + lr;
    const float init = (ct2 < 7 && c2 < CCC) ? (bo2[c2] + bl2[c2]) : 0.f;
    #pragma unroll
    for (int nt=0; nt<4; ++nt) o[i2][nt] = (f32x4){init, init, init, init};
  }

  // ---- branch 1 GEMM1: A = rightb (bf16, direct global), B = Wo1T ----
  #pragma unroll
  for (int cc=0; cc<2; ++cc){
    bf16x8 B[2][4];
    float b1c[2];
    #pragma unroll
    for (int ct=0; ct<2; ++ct){
      const int c = (w*4 + cc*2 + ct)*16 + lr;
      b1c[ct] = bo1[c];
      #pragma unroll
      for (int kk=0; kk<4; ++kk)
        B[ct][kk] = *reinterpret_cast<const bf16x8*>(Wo1T + (size_t)c*128 + kk*32 + lq*8);
    }
    #pragma unroll
    for (int nt=0; nt<4; ++nt){
      const int row = nt*16 + lr;
      f32x4 h0 = (f32x4){0.f,0.f,0.f,0.f}, h1 = h0;
      #pragma unroll
      for (int kk=0; kk<4; ++kk){
        const bf16x8 a = *reinterpret_cast<const bf16x8*>(
            rightb + (nb + row)*FF + kk*32 + lq*8);
        h0 = mfma16(a, B[0][kk], h0);
        h1 = mfma16(a, B[1][kk], h1);
      }
      scatter_h(sH, h0, b1c[0], ao, (w*4 + cc*2 + 0)*16 + lr, nt, lq);
      scatter_h(sH, h1, b1c[1], ao, (w*4 + cc*2 + 1)*16 + lr, nt, lq);
    }
  }
  __syncthreads();
  gemm2_accum(sH, Wo2T, o, w, lr, lq);
  __syncthreads();   // branch1 GEMM2 done reading sH before branch2 overwrites

  // ---- branch 2 GEMM1: A = label (fp32 -> bf16 in regs), B = Wl1T ----
  #pragma unroll
  for (int cc=0; cc<2; ++cc){
    bf16x8 B[2][4];
    float b1c[2];
    #pragma unroll
    for (int ct=0; ct<2; ++ct){
      const int c = (w*4 + cc*2 + ct)*16 + lr;
      b1c[ct] = bl1[c];
      #pragma unroll
      for (int kk=0; kk<4; ++kk)
        B[ct][kk] = *reinterpret_cast<const bf16x8*>(Wl1T + (size_t)c*128 + kk*32 + lq*8);
    }
    #pragma unroll
    for (int nt=0; nt<4; ++nt){
      const int row = nt*16 + lr;
      f32x4 h0 = (f32x4){0.f,0.f,0.f,0.f}, h1 = h0;
      #pragma unroll
      for (int kk=0; kk<4; ++kk){
        const bf16x8 a = label_frag(label, nb + row, kk, lq);
        h0 = mfma16(a, B[0][kk], h0);
        h1 = mfma16(a, B[1][kk], h1);
      }
      scatter_h(sH, h0, b1c[0], al, (w*4 + cc*2 + 0)*16 + lr, nt, lq);
      scatter_h(sH, h1, b1c[1], al, (w*4 + cc*2 + 1)*16 + lr, nt, lq);
    }
  }
  __syncthreads();
  gemm2_accum(sH, Wl2T, o, w, lr, lq);

  // store out (scattered dwords; 16-consecutive-float segments per lane group)
  #pragma unroll
  for (int i2=0; i2<2; ++i2){
    const int ct2 = 2*w + i2;
    const int c2 = ct2*16 + lr;
    if (ct2 < 7 && c2 < CCC){
      #pragma unroll
      for (int nt=0; nt<4; ++nt){
        #pragma unroll
        for (int j=0; j<4; ++j){
          const int n = nt*16 + lq*4 + j;
          out[(nb + n)*CCC + c2] = o[i2][nt][j];
        }
      }
    }
  }
}

extern "C" void kernel_launch(void* const* d_in, const int* in_sizes, int n_in,
                              void* d_out, int out_size, void* d_ws, size_t ws_size,
                              hipStream_t stream) {
  const float* feat  = (const float*)d_in[0];
  const float* label = (const float*)d_in[1];
  const float* Watt  = (const float*)d_in[2];
  const float* batt  = (const float*)d_in[3];
  const float* Wo1   = (const float*)d_in[4];
  const float* bo1   = (const float*)d_in[5];
  const float* aop   = (const float*)d_in[6];
  const float* Wo2   = (const float*)d_in[7];
  const float* bo2   = (const float*)d_in[8];
  const float* Wl1   = (const float*)d_in[9];
  const float* bl1   = (const float*)d_in[10];
  const float* alp   = (const float*)d_in[11];
  const float* Wl2   = (const float*)d_in[12];
  const float* bl2   = (const float*)d_in[13];
  float* out = (float*)d_out;

  unsigned short* rightb = (unsigned short*)d_ws;          // N*F bf16 = 51.2 MB
  unsigned short* Wo1T = rightb + (size_t)NN*FF;           // [256][128]
  unsigned short* Wl1T = Wo1T + 256*128;                   // [256][128]
  unsigned short* Wo2T = Wl1T + 256*128;                   // [112][256]
  unsigned short* Wl2T = Wo2T + 112*256;                   // [112][256]

  prep_weights<<<128, 256, 0, stream>>>(Wo1, Wl1, Wo2, Wl2, Wo1T, Wl1T, Wo2T, Wl2T);
  attn_right_kernel<<<NN/4, 256, 0, stream>>>(feat, Watt, batt, rightb);
  mlp_mfma_kernel<<<NN/64, 256, 0, stream>>>(rightb, label,
                                             Wo1T, bo1, aop, Wo2T, bo2,
                                             Wl1T, bl1, alp, Wl2T, bl2, out);
}

// Round 8
// 346.572 us; speedup vs baseline: 1.3648x; 1.3342x over previous
//
#include <hip/hip_runtime.h>
#include <hip/hip_bf16.h>
#include <cstddef>

#define NHOP 10
#define NN 200000
#define FF 128
#define HIDD 256
#define CCC 100
#define NEG_SLOPE_C 0.2f

typedef __attribute__((ext_vector_type(8))) short bf16x8;   // 8 bf16 = 4 VGPR
typedef __attribute__((ext_vector_type(4))) short bf16x4;
typedef __attribute__((ext_vector_type(4))) float f32x4;

__device__ __forceinline__ short f2bfs(float x){
  return __builtin_bit_cast(short, __float2bfloat16(x));    // native v_cvt, RNE
}
__device__ __forceinline__ float bf2f(short s){
  return __uint_as_float(((unsigned)(unsigned short)s) << 16);
}
__device__ __forceinline__ f32x4 mfma16(bf16x8 a, bf16x8 b, f32x4 c){
  return __builtin_amdgcn_mfma_f32_16x16x32_bf16(a, b, c, 0, 0, 0);
}
__device__ __forceinline__ float leakyf(float x){ return x >= 0.f ? x : NEG_SLOPE_C*x; }

// ---------------- Kernel 0: weight prep (bf16 + transpose + pad) ----------------
__global__ __launch_bounds__(256) void prep_weights(
    const float* __restrict__ Wo1, const float* __restrict__ Wl1,
    const float* __restrict__ Wo2, const float* __restrict__ Wl2,
    unsigned short* __restrict__ Wo1T, unsigned short* __restrict__ Wl1T,
    unsigned short* __restrict__ Wo2T, unsigned short* __restrict__ Wl2T)
{
  const int id = blockIdx.x*256 + threadIdx.x;          // 0..32767
  {
    const int c = id >> 7, k = id & 127;                // layout [256][128]
    Wo1T[id] = (unsigned short)f2bfs(Wo1[(size_t)k*HIDD + c]);           // Wo1 [128][256]
    Wl1T[id] = (k < CCC) ? (unsigned short)f2bfs(Wl1[(size_t)k*HIDD + c]) : 0;  // pad k
  }
  if (id < 112*256){
    const int c = id >> 8, k = id & 255;                // layout [112][256]
    Wo2T[id] = (c < CCC) ? (unsigned short)f2bfs(Wo2[(size_t)k*CCC + c]) : 0;   // pad c
    Wl2T[id] = (c < CCC) ? (unsigned short)f2bfs(Wl2[(size_t)k*CCC + c]) : 0;
  }
}

// ---------------- Kernel 1: hop attention -> right (N x F, bf16) ----------------
// R4-proven attn4: 4 nodes/wave, 16 lanes/node, float4 loads (16B/lane x2),
// 4-stage butterfly, features cached bf16 for the right-accum.
__global__ __launch_bounds__(256) void attn_right_kernel(
    const float* __restrict__ feat,   // H,N,F
    const float* __restrict__ Watt,   // 2F
    const float* __restrict__ batt,   // 1
    unsigned short* __restrict__ rightb)  // N,F bf16
{
  const int lane = threadIdx.x & 63;
  const int w = threadIdx.x >> 6;
  const int nl = lane >> 4, fl = lane & 15;
  const int n = blockIdx.x*16 + w*4 + nl;               // 12500*16 = 200000 exact

  const float4 w1a = *reinterpret_cast<const float4*>(Watt + fl*4);
  const float4 w1b = *reinterpret_cast<const float4*>(Watt + 64 + fl*4);
  const float4 w2a = *reinterpret_cast<const float4*>(Watt + FF + fl*4);
  const float4 w2b = *reinterpret_cast<const float4*>(Watt + FF + 64 + fl*4);
  const float b = batt[0];

  float p1[NHOP], p2[NHOP];
  bf16x8 fbf[NHOP];
  const float* fp = feat + (size_t)n*FF;
  #pragma unroll
  for (int i=0;i<NHOP;i++){
    const float* hp = fp + (size_t)i*((size_t)NN*FF);
    const float4 va = *reinterpret_cast<const float4*>(hp + fl*4);
    const float4 vb = *reinterpret_cast<const float4*>(hp + 64 + fl*4);
    p1[i] = va.x*w1a.x + va.y*w1a.y + va.z*w1a.z + va.w*w1a.w
          + vb.x*w1b.x + vb.y*w1b.y + vb.z*w1b.z + vb.w*w1b.w;
    p2[i] = va.x*w2a.x + va.y*w2a.y + va.z*w2a.z + va.w*w2a.w
          + vb.x*w2b.x + vb.y*w2b.y + vb.z*w2b.z + vb.w*w2b.w;
    fbf[i][0]=f2bfs(va.x); fbf[i][1]=f2bfs(va.y); fbf[i][2]=f2bfs(va.z); fbf[i][3]=f2bfs(va.w);
    fbf[i][4]=f2bfs(vb.x); fbf[i][5]=f2bfs(vb.y); fbf[i][6]=f2bfs(vb.z); fbf[i][7]=f2bfs(vb.w);
  }
  // butterfly all-reduce within each 16-lane group
  #pragma unroll
  for (int m=8;m>0;m>>=1){
    #pragma unroll
    for (int i=0;i<NHOP;i++){
      p1[i] += __shfl_xor(p1[i], m, 64);
      p2[i] += __shfl_xor(p2[i], m, 64);
    }
  }
  // scalar recurrence (replicated across the 16 lanes of this node)
  float sc[NHOP];
  sc[0] = leakyf(p1[0] + p2[0] + b);
  #pragma unroll
  for (int i=1;i<NHOP;i++){
    float mx = sc[0];
    #pragma unroll
    for (int j=1;j<i;j++) mx = fmaxf(mx, sc[j]);
    float Z = 0.f, hs = 0.f;
    #pragma unroll
    for (int j=0;j<i;j++){
      const float e = __expf(sc[j]-mx);
      Z += e;
      hs = fmaf(e, p1[j], hs);
    }
    sc[i] = leakyf(hs/Z + p2[i] + b);
  }
  float mx = sc[0];
  #pragma unroll
  for (int j=1;j<NHOP;j++) mx = fmaxf(mx, sc[j]);
  float Z = 0.f;
  float e[NHOP];
  #pragma unroll
  for (int j=0;j<NHOP;j++){ e[j] = __expf(sc[j]-mx); Z += e[j]; }
  const float inv = 1.f/Z;
  float racc[8];
  #pragma unroll
  for (int u=0;u<8;u++) racc[u] = 0.f;
  #pragma unroll
  for (int j=0;j<NHOP;j++){
    const float a = e[j]*inv;
    #pragma unroll
    for (int u=0;u<8;u++) racc[u] = fmaf(a, bf2f(fbf[j][u]), racc[u]);
  }
  bf16x4 sa, sb;
  sa[0]=f2bfs(racc[0]); sa[1]=f2bfs(racc[1]); sa[2]=f2bfs(racc[2]); sa[3]=f2bfs(racc[3]);
  sb[0]=f2bfs(racc[4]); sb[1]=f2bfs(racc[5]); sb[2]=f2bfs(racc[6]); sb[3]=f2bfs(racc[7]);
  *reinterpret_cast<bf16x4*>(rightb + (size_t)n*FF + fl*4) = sa;
  *reinterpret_cast<bf16x4*>(rightb + (size_t)n*FF + 64 + fl*4) = sb;
}

// ---------------- Kernel 2: MFMA MLP (R3-proven mlpA: LDS-staged A, B hoisted) ----------------
__device__ __forceinline__ void mlp_branch(
    const unsigned short* sA, unsigned short* sH,
    const unsigned short* __restrict__ W1T, const float* __restrict__ b1, const float alpha,
    const unsigned short* __restrict__ W2T,
    f32x4 (&o)[2][4], const int w, const int lr, const int lq)
{
  // ---- GEMM1: [64 x 128] @ [128 x 256] -> h (prelu, bf16 to LDS) ----
  bf16x8 B[4][4];
  float b1c[4];
  #pragma unroll
  for (int ctl=0; ctl<4; ++ctl){
    const int c = (4*w+ctl)*16 + lr;
    b1c[ctl] = b1[c];
    #pragma unroll
    for (int kk=0; kk<4; ++kk)
      B[ctl][kk] = *reinterpret_cast<const bf16x8*>(W1T + (size_t)c*128 + kk*32 + lq*8);
  }
  #pragma unroll
  for (int nt=0; nt<4; ++nt){
    f32x4 h[4];
    #pragma unroll
    for (int ctl=0; ctl<4; ++ctl) h[ctl] = (f32x4){0.f,0.f,0.f,0.f};
    const int row = nt*16 + lr;
    #pragma unroll
    for (int kk=0; kk<4; ++kk){
      const bf16x8 a = *reinterpret_cast<const bf16x8*>(
          (const char*)sA + row*256 + ((kk*64 + lq*16) ^ ((row&7)<<4)));
      #pragma unroll
      for (int ctl=0; ctl<4; ++ctl)
        h[ctl] = mfma16(a, B[ctl][kk], h[ctl]);
    }
    // prelu + scatter bf16 into swizzled sH[n][k]
    #pragma unroll
    for (int ctl=0; ctl<4; ++ctl){
      const int c = (4*w+ctl)*16 + lr;
      #pragma unroll
      for (int j=0; j<4; ++j){
        float v = h[ctl][j] + b1c[ctl];
        v = v >= 0.f ? v : alpha*v;
        const int n = nt*16 + lq*4 + j;
        *reinterpret_cast<unsigned short*>(
            (char*)sH + n*512 + ((2*c) ^ ((n&7)<<4))) = (unsigned short)f2bfs(v);
      }
    }
  }
  __syncthreads();   // h complete (cross-wave rows)
  // ---- GEMM2: [64 x 256] @ [256 x 112] accumulate into o ----
  #pragma unroll
  for (int i2=0; i2<2; ++i2){
    const int ct2 = 2*w + i2;
    if (ct2 < 7){
      bf16x8 b2[8];
      #pragma unroll
      for (int kk=0; kk<8; ++kk)
        b2[kk] = *reinterpret_cast<const bf16x8*>(W2T + (size_t)(ct2*16+lr)*256 + kk*32 + lq*8);
      #pragma unroll
      for (int nt=0; nt<4; ++nt){
        const int row = nt*16 + lr;
        #pragma unroll
        for (int kk=0; kk<8; ++kk){
          const bf16x8 a2 = *reinterpret_cast<const bf16x8*>(
              (const char*)sH + row*512 + ((kk*64 + lq*16) ^ ((row&7)<<4)));
          o[i2][nt] = mfma16(a2, b2[kk], o[i2][nt]);
        }
      }
    }
  }
}

__global__ __launch_bounds__(256) void mlp_mfma_kernel(
    const unsigned short* __restrict__ rightb, const float* __restrict__ label,
    const unsigned short* __restrict__ Wo1T, const float* __restrict__ bo1, const float* __restrict__ aop,
    const unsigned short* __restrict__ Wo2T, const float* __restrict__ bo2,
    const unsigned short* __restrict__ Wl1T, const float* __restrict__ bl1, const float* __restrict__ alp,
    const unsigned short* __restrict__ Wl2T, const float* __restrict__ bl2,
    float* __restrict__ out)
{
  __shared__ __align__(16) unsigned short sA[64*128];   // 16 KB staged A (swizzled)
  __shared__ __align__(16) unsigned short sH[64*256];   // 32 KB h (swizzled)
  const int t = threadIdx.x;
  const int w = t >> 6, lane = t & 63, lr = lane & 15, lq = lane >> 4;
  const size_t nb = (size_t)blockIdx.x * 64;

  // init out accumulators with final biases
  f32x4 o[2][4];
  #pragma unroll
  for (int i2=0; i2<2; ++i2){
    const int ct2 = 2*w + i2;
    const int c2 = ct2*16 + lr;
    const float init = (ct2 < 7 && c2 < CCC) ? (bo2[c2] + bl2[c2]) : 0.f;
    #pragma unroll
    for (int nt=0; nt<4; ++nt) o[i2][nt] = (f32x4){init, init, init, init};
  }

  // stage right tile (bf16, swizzled)
  {
    const unsigned short* src = rightb + nb*FF;
    #pragma unroll
    for (int i=0;i<4;i++){
      const int chunk = t + 256*i;
      const int row = chunk >> 4, cs = chunk & 15;
      const bf16x8 v = *reinterpret_cast<const bf16x8*>(src + row*FF + cs*8);
      *reinterpret_cast<bf16x8*>((char*)sA + row*256 + ((cs*16) ^ ((row&7)<<4))) = v;
    }
  }
  __syncthreads();
  mlp_branch(sA, sH, Wo1T, bo1, aop[0], Wo2T, o, w, lr, lq);

  // stage label tile (fp32 -> bf16, swizzled, zero-pad cols 100..127)
  {
    #pragma unroll
    for (int i=0;i<7;i++){
      const int idx = t + 256*i;
      if (idx < 1600){
        const int row = idx/25, c0 = (idx%25)*4;
        const float4 v = *reinterpret_cast<const float4*>(label + (nb+row)*CCC + c0);
        bf16x4 p;
        p[0] = f2bfs(v.x); p[1] = f2bfs(v.y);
        p[2] = f2bfs(v.z); p[3] = f2bfs(v.w);
        *reinterpret_cast<bf16x4*>((char*)sA + row*256 + ((2*c0) ^ ((row&7)<<4))) = p;
      }
    }
    for (int idx = t; idx < 448; idx += 256){
      const int row = idx/7, ch = idx%7;
      *reinterpret_cast<bf16x4*>((char*)sA + row*256 + ((200 + 8*ch) ^ ((row&7)<<4))) = (bf16x4){0,0,0,0};
    }
  }
  __syncthreads();   // also guarantees all waves done reading sH of branch 1
  mlp_branch(sA, sH, Wl1T, bl1, alp[0], Wl2T, o, w, lr, lq);

  // store out (scattered dwords; 16-consecutive-float segments per lane group)
  #pragma unroll
  for (int i2=0; i2<2; ++i2){
    const int ct2 = 2*w + i2;
    const int c2 = ct2*16 + lr;
    if (ct2 < 7 && c2 < CCC){
      #pragma unroll
      for (int nt=0; nt<4; ++nt){
        #pragma unroll
        for (int j=0; j<4; ++j){
          const int n = nt*16 + lq*4 + j;
          out[(nb + n)*CCC + c2] = o[i2][nt][j];
        }
      }
    }
  }
}

extern "C" void kernel_launch(void* const* d_in, const int* in_sizes, int n_in,
                              void* d_out, int out_size, void* d_ws, size_t ws_size,
                              hipStream_t stream) {
  const float* feat  = (const float*)d_in[0];
  const float* label = (const float*)d_in[1];
  const float* Watt  = (const float*)d_in[2];
  const float* batt  = (const float*)d_in[3];
  const float* Wo1   = (const float*)d_in[4];
  const float* bo1   = (const float*)d_in[5];
  const float* aop   = (const float*)d_in[6];
  const float* Wo2   = (const float*)d_in[7];
  const float* bo2   = (const float*)d_in[8];
  const float* Wl1   = (const float*)d_in[9];
  const float* bl1   = (const float*)d_in[10];
  const float* alp   = (const float*)d_in[11];
  const float* Wl2   = (const float*)d_in[12];
  const float* bl2   = (const float*)d_in[13];
  float* out = (float*)d_out;

  unsigned short* rightb = (unsigned short*)d_ws;          // N*F bf16 = 51.2 MB
  unsigned short* Wo1T = rightb + (size_t)NN*FF;           // [256][128]
  unsigned short* Wl1T = Wo1T + 256*128;                   // [256][128]
  unsigned short* Wo2T = Wl1T + 256*128;                   // [112][256]
  unsigned short* Wl2T = Wo2T + 112*256;                   // [112][256]

  prep_weights<<<128, 256, 0, stream>>>(Wo1, Wl1, Wo2, Wl2, Wo1T, Wl1T, Wo2T, Wl2T);
  attn_right_kernel<<<NN/16, 256, 0, stream>>>(feat, Watt, batt, rightb);
  mlp_mfma_kernel<<<NN/64, 256, 0, stream>>>(rightb, label,
                                             Wo1T, bo1, aop, Wo2T, bo2,
                                             Wl1T, bl1, alp, Wl2T, bl2, out);
}